// Round 11
// baseline (455.308 us; speedup 1.0000x reference)
//
#include <hip/hip_runtime.h>
#include <cstdint>
#include <cstddef>

#define M_DIM 4096
#define N_DIM 16384
#define K_DIM 4096
#define NBLK_Q 128

#define BM 256
#define BN 256
#define BK 64
#define KSTEPS (K_DIM / BK)  // 64
#define BUFB 32768           // [A s0 8K | B s0 8K | A s1 8K | B s1 8K]
#define NBUF 2               // 64 KB LDS

typedef int i32x4 __attribute__((ext_vector_type(4)));
typedef int i32x16 __attribute__((ext_vector_type(16)));

#define SFENCE() __builtin_amdgcn_sched_barrier(0)

// ---- pre-pass 1: per-row int8 quant of x, scattered into staged-tile order ----
// A8S = [mtile 16][k32 128][m32 8][kg 2][row 32][16B]: element (m, k) with
// m = mtile*256+m32*32+row, k = k32*32+kg*16+j at byte j.
__global__ __launch_bounds__(256) void quant_x(const float* __restrict__ x,
                                               char* __restrict__ A8S,
                                               float* __restrict__ sxr) {
  const int m = blockIdx.x;
  const int t = threadIdx.x;
  const float* xr = x + (size_t)m * K_DIM + t * 16;
  float4 v[4];
#pragma unroll
  for (int i = 0; i < 4; ++i) v[i] = ((const float4*)xr)[i];
  float amax = 0.f;
#pragma unroll
  for (int i = 0; i < 4; ++i)
    amax = fmaxf(amax, fmaxf(fmaxf(fabsf(v[i].x), fabsf(v[i].y)),
                             fmaxf(fabsf(v[i].z), fabsf(v[i].w))));
#pragma unroll
  for (int off = 32; off; off >>= 1) amax = fmaxf(amax, __shfl_xor(amax, off, 64));
  __shared__ float wmax[4];
  if ((t & 63) == 0) wmax[t >> 6] = amax;
  __syncthreads();
  amax = fmaxf(fmaxf(wmax[0], wmax[1]), fmaxf(wmax[2], wmax[3]));
  const float inv = 127.0f / amax;  // amax > 0 for gaussian inputs
  if (t == 0) sxr[m] = amax / 127.0f;
  unsigned d[4];
#pragma unroll
  for (int i = 0; i < 4; ++i) {
    int q0 = (int)rintf(v[i].x * inv), q1 = (int)rintf(v[i].y * inv);
    int q2 = (int)rintf(v[i].z * inv), q3 = (int)rintf(v[i].w * inv);
    d[i] = (q0 & 0xff) | ((q1 & 0xff) << 8) | ((q2 & 0xff) << 16) | ((q3 & 0xff) << 24);
  }
  const int k32 = t >> 1, kg = t & 1;
  const int mtile = m >> 8, mm = m & 255, m32 = mm >> 5, r = mm & 31;
  int4* dst = (int4*)(A8S + ((size_t)(mtile * 128 + k32)) * 8192 + m32 * 1024 + kg * 512 + r * 16);
  *dst = make_int4(d[0], d[1], d[2], d[3]);
}

// ---- pre-pass 2: W requant to per-column scale, staged-tile order ----
// S[o] = max_nb s[o,nb]; w8 = rint(q * s/S). B8S = [ntile 64][k32 128][n32 8][kg 2][col 32][16B].
__global__ __launch_bounds__(256) void pack_w8(const int* __restrict__ qs,
                                               const float* __restrict__ scales,
                                               char* __restrict__ B8S,
                                               float* __restrict__ swc) {
  const int o = blockIdx.x * 4 + (threadIdx.x >> 6);
  const int l = threadIdx.x & 63;
  const float s0 = scales[(size_t)o * NBLK_Q + l];
  const float s1 = scales[(size_t)o * NBLK_Q + 64 + l];
  float S = fmaxf(s0, s1);
#pragma unroll
  for (int off = 32; off; off >>= 1) S = fmaxf(S, __shfl_xor(S, off, 64));
  if (l == 0) swc[o] = S;
  const float rS = 1.0f / S;
  const int nt = o >> 8, col = o & 255, n32 = col >> 5, c = col & 31;
#pragma unroll
  for (int h = 0; h < 2; ++h) {
    const int nb = l + 64 * h;
    const float ratio = ((h == 0) ? s0 : s1) * rS;
    const int4* q = (const int4*)(qs + ((size_t)o * NBLK_Q + nb) * 32);
    unsigned d[8];
#pragma unroll
    for (int g = 0; g < 8; ++g) {
      int4 v = q[g];
      int a0 = (int)rintf((float)v.x * ratio);
      int a1 = (int)rintf((float)v.y * ratio);
      int a2 = (int)rintf((float)v.z * ratio);
      int a3 = (int)rintf((float)v.w * ratio);
      d[g] = (a0 & 0xff) | ((a1 & 0xff) << 8) | ((a2 & 0xff) << 16) | ((a3 & 0xff) << 24);
    }
    char* dst = B8S + ((size_t)(nt * 128 + nb)) * 8192 + n32 * 1024 + c * 16;
    ((int4*)dst)[0] = make_int4(d[0], d[1], d[2], d[3]);
    ((int4*)(dst + 512))[0] = make_int4(d[4], d[5], d[6], d[7]);
  }
}

// ---- main GEMM: y = sx[m]*S[o]*(A8 . W8^T) + bias — pure i8 MFMA ----
// 256x256, BK=64, 8 waves (2Mx4N), per-wave 128x64 = 4x2 tiles of 32x32,
// mfma_i32_32x32x32_i8, 16 MFMA/wave/step, acc 128 regs.
// REG-STAGING (not global_load_lds: that path is capped at ~95 cy per 1KB
// instruction ~ 10.5 B/cy/CU, measured invariant across R2/R6/R9/R10/m97):
// per step {ds_read frags(kt); 4x global_load_dwordx4 tile kt+1 -> regs}
// SFENCE {16 MFMA} SFENCE {4x ds_write_b128 -> other buffer; __syncthreads}.
// Loads issue before the MFMA cluster, their vmcnt wait lands after it (fence)
// -> HBM/L2 latency hides under 1165 cy of MFMA. One barrier per step; 2 LDS
// buffers: writes target the buffer whose reads completed last step (before
// that step's barrier). syncthreads' full drain is free here (loads already
// consumed by the ds_writes). Tail: kt=63 re-loads tile 63 into buf0 (never
// read again) - benign, keeps code branchless.
// Grid: XCD-partitioned for L2 residency: XCD x owns mtiles {2x,2x+1} x all
// ntiles; pair blocks (2x,nt),(2x+1,nt) adjacent -> B-tile 2-way L2 reuse;
// A-tile pair (2MB) L2-resident with 16-way reuse across the ntile sweep.
__global__ __launch_bounds__(512, 2) void gemm_i8(
    const char* __restrict__ A8S, const char* __restrict__ B8S,
    const float* __restrict__ sxr, const float* __restrict__ swc,
    const float* __restrict__ bias, float* __restrict__ C) {
  __shared__ __align__(16) char lds[NBUF * BUFB];  // 64 KB

  const int tid = threadIdx.x;
  const int w = tid >> 6;
  const int l = tid & 63;
  const int wm = w >> 2;  // 0..1
  const int wn = w & 3;   // 0..3

  // XCD-partitioned bijective grid (1024 blocks): bid = 8k + xcd
  const int bid = blockIdx.x;
  const int xcd = bid & 7;
  const int k = bid >> 3;          // 0..127
  const int mtile = xcd * 2 + (k & 1);
  const int ntile = k >> 1;
  const int brow = mtile * BM;
  const int bcol = ntile * BN;

  // per-thread staging addresses: wave w moves the 1KB chunk of sub-tile
  // m32=w (resp n32=w) in each k-slab; all accesses contiguous 1KB/wave.
  const char* srcA = A8S + (size_t)mtile * 128 * 8192 + w * 1024 + l * 16;
  const char* srcB = B8S + (size_t)ntile * 128 * 8192 + w * 1024 + l * 16;
  const int doff = w * 1024 + l * 16;

  i32x16 acc[4][2] = {};

  // prologue: tile 0 -> buf0
  {
    int4 ra0 = *(const int4*)(srcA);
    int4 ra1 = *(const int4*)(srcA + 8192);
    int4 rb0 = *(const int4*)(srcB);
    int4 rb1 = *(const int4*)(srcB + 8192);
    *(int4*)(lds + doff) = ra0;
    *(int4*)(lds + 16384 + doff) = ra1;
    *(int4*)(lds + 8192 + doff) = rb0;
    *(int4*)(lds + 24576 + doff) = rb1;
    __syncthreads();
  }

  for (int kt = 0; kt < KSTEPS; ++kt) {
    const char* bb = lds + (kt & 1) * BUFB;

    // ds_read current fragments
    i32x4 a[2][4], b[2][2];
#pragma unroll
    for (int s = 0; s < 2; ++s) {
#pragma unroll
      for (int i = 0; i < 4; ++i)
        a[s][i] = *(const i32x4*)(bb + s * 16384 + (wm * 4 + i) * 1024 + l * 16);
#pragma unroll
      for (int j = 0; j < 2; ++j)
        b[s][j] = *(const i32x4*)(bb + s * 16384 + 8192 + (wn * 2 + j) * 1024 + l * 16);
    }

    // issue next-tile global loads (consumed only after the MFMA cluster)
    const int qn = (kt + 1 > KSTEPS - 1) ? (KSTEPS - 1) : (kt + 1);
    const size_t go = (size_t)qn * 16384;
    int4 ra0 = *(const int4*)(srcA + go);
    int4 ra1 = *(const int4*)(srcA + go + 8192);
    int4 rb0 = *(const int4*)(srcB + go);
    int4 rb1 = *(const int4*)(srcB + go + 8192);

    SFENCE();
    __builtin_amdgcn_s_setprio(1);
#pragma unroll
    for (int i = 0; i < 4; ++i)
#pragma unroll
      for (int j = 0; j < 2; ++j) {
        acc[i][j] = __builtin_amdgcn_mfma_i32_32x32x32_i8(a[0][i], b[0][j], acc[i][j], 0, 0, 0);
        acc[i][j] = __builtin_amdgcn_mfma_i32_32x32x32_i8(a[1][i], b[1][j], acc[i][j], 0, 0, 0);
      }
    __builtin_amdgcn_s_setprio(0);
    SFENCE();

    // write tile kt+1 into the other buffer (its last reads were step kt-1)
    char* nb = lds + ((kt + 1) & 1) * BUFB;
    *(int4*)(nb + doff) = ra0;
    *(int4*)(nb + 16384 + doff) = ra1;
    *(int4*)(nb + 8192 + doff) = rb0;
    *(int4*)(nb + 24576 + doff) = rb1;
    __syncthreads();
  }

  // epilogue: 32x32 C/D layout col = lane&31, row = (reg&3)+8*(reg>>2)+4*(lane>>5)
#pragma unroll
  for (int i = 0; i < 4; ++i) {
    const int rb = brow + wm * 128 + i * 32 + 4 * (l >> 5);
#pragma unroll
    for (int j = 0; j < 2; ++j) {
      const int col = bcol + wn * 64 + j * 32 + (l & 31);
      const float Sw = swc[col];
      const float bv = bias[col];
#pragma unroll
      for (int r = 0; r < 16; ++r) {
        const int row = rb + (r & 3) + 8 * (r >> 2);
        C[(size_t)row * N_DIM + col] = (float)acc[i][j][r] * (sxr[row] * Sw) + bv;
      }
    }
  }
}

// ---- fallback (ws too small): exact fp32, slow but correct ----
__global__ void naive_gemm(const float* __restrict__ x, const int* __restrict__ qs,
                           const float* __restrict__ scales, const float* __restrict__ bias,
                           float* __restrict__ y) {
  size_t idx = (size_t)blockIdx.x * 256 + threadIdx.x;
  if (idx >= (size_t)M_DIM * N_DIM) return;
  int o = (int)(idx % N_DIM);
  size_t m = idx / N_DIM;
  const float* xr = x + m * K_DIM;
  const int* q = qs + (size_t)o * K_DIM;
  const float* sc = scales + (size_t)o * NBLK_Q;
  float sum = 0.f;
  for (int nb = 0; nb < NBLK_Q; ++nb) {
    float s = sc[nb];
    float bs = 0.f;
#pragma unroll 8
    for (int b = 0; b < 32; ++b) bs += xr[nb * 32 + b] * (float)q[nb * 32 + b];
    sum += s * bs;
  }
  y[idx] = sum + bias[o];
}

extern "C" void kernel_launch(void* const* d_in, const int* in_sizes, int n_in,
                              void* d_out, int out_size, void* d_ws, size_t ws_size,
                              hipStream_t stream) {
  const float* x = (const float*)d_in[0];
  const int* qs = (const int*)d_in[1];
  const float* scales = (const float*)d_in[2];
  const float* bias = (const float*)d_in[3];
  float* y = (float*)d_out;

  const size_t A8_bytes = (size_t)M_DIM * K_DIM;   // 16 MB
  const size_t B8_bytes = (size_t)N_DIM * K_DIM;   // 64 MB
  const size_t SX_bytes = (size_t)M_DIM * 4;
  const size_t SW_bytes = (size_t)N_DIM * 4;

  if (ws_size < A8_bytes + B8_bytes + SX_bytes + SW_bytes) {
    size_t total = (size_t)M_DIM * N_DIM;
    naive_gemm<<<(unsigned)((total + 255) / 256), 256, 0, stream>>>(x, qs, scales, bias, y);
    return;
  }

  char* A8S = (char*)d_ws;
  char* B8S = A8S + A8_bytes;
  float* sxr = (float*)(B8S + B8_bytes);
  float* swc = (float*)((char*)sxr + SX_bytes);

  quant_x<<<M_DIM, 256, 0, stream>>>(x, A8S, sxr);
  pack_w8<<<N_DIM / 4, 256, 0, stream>>>(qs, scales, B8S, swc);
  gemm_i8<<<(M_DIM / BM) * (N_DIM / BN), 512, 0, stream>>>(A8S, B8S, sxr, swc, bias, y);
}

// Round 12
// 425.011 us; speedup vs baseline: 1.0713x; 1.0713x over previous
//
#include <hip/hip_runtime.h>
#include <cstdint>
#include <cstddef>

#define M_DIM 4096
#define N_DIM 16384
#define K_DIM 4096
#define NBLK_Q 128

#define BM 256
#define BN 256
#define BK 32
#define KSTEPS (K_DIM / BK)  // 128
#define BUFB 16384           // [A 8KB | B 8KB]
#define NBUF 4               // 64 KB LDS

typedef int i32x4 __attribute__((ext_vector_type(4)));
typedef int i32x16 __attribute__((ext_vector_type(16)));

#define SFENCE() __builtin_amdgcn_sched_barrier(0)
#define BAR() __builtin_amdgcn_s_barrier()
#define WAITVM(n) asm volatile("s_waitcnt vmcnt(" #n ")")
#define WAITLG0() asm volatile("s_waitcnt lgkmcnt(0)")

// ---- pre-pass 1: per-row int8 quant of x, scattered into staged-tile order ----
// A8S = [mtile 16][k32 128][m32 8][kg 2][row 32][16B]
__global__ __launch_bounds__(256) void quant_x(const float* __restrict__ x,
                                               char* __restrict__ A8S,
                                               float* __restrict__ sxr) {
  const int m = blockIdx.x;
  const int t = threadIdx.x;
  const float* xr = x + (size_t)m * K_DIM + t * 16;
  float4 v[4];
#pragma unroll
  for (int i = 0; i < 4; ++i) v[i] = ((const float4*)xr)[i];
  float amax = 0.f;
#pragma unroll
  for (int i = 0; i < 4; ++i)
    amax = fmaxf(amax, fmaxf(fmaxf(fabsf(v[i].x), fabsf(v[i].y)),
                             fmaxf(fabsf(v[i].z), fabsf(v[i].w))));
#pragma unroll
  for (int off = 32; off; off >>= 1) amax = fmaxf(amax, __shfl_xor(amax, off, 64));
  __shared__ float wmax[4];
  if ((t & 63) == 0) wmax[t >> 6] = amax;
  __syncthreads();
  amax = fmaxf(fmaxf(wmax[0], wmax[1]), fmaxf(wmax[2], wmax[3]));
  const float inv = 127.0f / amax;
  if (t == 0) sxr[m] = amax / 127.0f;
  unsigned d[4];
#pragma unroll
  for (int i = 0; i < 4; ++i) {
    int q0 = (int)rintf(v[i].x * inv), q1 = (int)rintf(v[i].y * inv);
    int q2 = (int)rintf(v[i].z * inv), q3 = (int)rintf(v[i].w * inv);
    d[i] = (q0 & 0xff) | ((q1 & 0xff) << 8) | ((q2 & 0xff) << 16) | ((q3 & 0xff) << 24);
  }
  const int k32 = t >> 1, kg = t & 1;
  const int mtile = m >> 8, mm = m & 255, m32 = mm >> 5, r = mm & 31;
  int4* dst = (int4*)(A8S + ((size_t)(mtile * 128 + k32)) * 8192 + m32 * 1024 + kg * 512 + r * 16);
  *dst = make_int4(d[0], d[1], d[2], d[3]);
}

// ---- pre-pass 2: W requant to per-column scale, staged-tile order ----
// B8S = [ntile 64][k32 128][n32 8][kg 2][col 32][16B]
__global__ __launch_bounds__(256) void pack_w8(const int* __restrict__ qs,
                                               const float* __restrict__ scales,
                                               char* __restrict__ B8S,
                                               float* __restrict__ swc) {
  const int o = blockIdx.x * 4 + (threadIdx.x >> 6);
  const int l = threadIdx.x & 63;
  const float s0 = scales[(size_t)o * NBLK_Q + l];
  const float s1 = scales[(size_t)o * NBLK_Q + 64 + l];
  float S = fmaxf(s0, s1);
#pragma unroll
  for (int off = 32; off; off >>= 1) S = fmaxf(S, __shfl_xor(S, off, 64));
  if (l == 0) swc[o] = S;
  const float rS = 1.0f / S;
  const int nt = o >> 8, col = o & 255, n32 = col >> 5, c = col & 31;
#pragma unroll
  for (int h = 0; h < 2; ++h) {
    const int nb = l + 64 * h;
    const float ratio = ((h == 0) ? s0 : s1) * rS;
    const int4* q = (const int4*)(qs + ((size_t)o * NBLK_Q + nb) * 32);
    unsigned d[8];
#pragma unroll
    for (int g = 0; g < 8; ++g) {
      int4 v = q[g];
      int a0 = (int)rintf((float)v.x * ratio);
      int a1 = (int)rintf((float)v.y * ratio);
      int a2 = (int)rintf((float)v.z * ratio);
      int a3 = (int)rintf((float)v.w * ratio);
      d[g] = (a0 & 0xff) | ((a1 & 0xff) << 8) | ((a2 & 0xff) << 16) | ((a3 & 0xff) << 24);
    }
    char* dst = B8S + ((size_t)(nt * 128 + nb)) * 8192 + n32 * 1024 + c * 16;
    ((int4*)dst)[0] = make_int4(d[0], d[1], d[2], d[3]);
    ((int4*)(dst + 512))[0] = make_int4(d[4], d[5], d[6], d[7]);
  }
}

// ---- main GEMM: intra-wave ILP pipeline, pure i8 MFMA ----
// 256x256, BK=32 (128 steps), 8 waves 2Mx4N, per-wave 128x64 = 4x2 of 32x32,
// 8 mfma_i32_32x32x32_i8 per step. Frags double-buffered in registers:
// step kt = { ds_read frags(kt+1) [6xb128, overlap MFMA]; global_load
// tile(kt+3) [2xdwordx4]; SFENCE; 8 MFMA frags(kt); SFENCE; vmcnt(2)
// [tile(kt+2) regs landed]; 2x ds_write tile(kt+2); lgkm(0) [writes visible
// pre-barrier; frag reads done anyway]; BAR }. 4x16KB buffers: read (kt+1)&3
// written one barrier ago; write (kt+2)&3 whose last real reads finished two
// barriers ago. vmcnt never 0; lgkm-wait sits AFTER the MFMA cluster -> LDS
// pipe overlaps MFMA within each wave (breaks R2-R11's pipe serialization:
// 3094 cy/step = sum of pipes; target max(768 LDS, 516 MFMA) + eps).
// Manual unroll-2 with named reg sets (no runtime-indexed arrays, rule #20).
// Tail: load/write indices clamped to 127; dups land in buffers whose future
// reads are dead (hand-traced kt=124..127). Grid: XCD-partitioned (R11,
// FETCH 295MB proven): XCD x owns mtiles {2x,2x+1} x all ntiles.
__global__ __launch_bounds__(512, 2) void gemm_i8(
    const char* __restrict__ A8S, const char* __restrict__ B8S,
    const float* __restrict__ sxr, const float* __restrict__ swc,
    const float* __restrict__ bias, float* __restrict__ C) {
  __shared__ __align__(16) char lds[NBUF * BUFB];  // 64 KB

  const int tid = threadIdx.x;
  const int w = tid >> 6;
  const int l = tid & 63;
  const int wm = w >> 2;  // 0..1
  const int wn = w & 3;   // 0..3

  const int bid = blockIdx.x;
  const int xcd = bid & 7;
  const int k = bid >> 3;
  const int mtile = xcd * 2 + (k & 1);
  const int ntile = k >> 1;
  const int brow = mtile * BM;
  const int bcol = ntile * BN;

  const char* srcA = A8S + (size_t)mtile * 128 * 8192 + w * 1024 + l * 16;
  const char* srcB = B8S + (size_t)ntile * 128 * 8192 + w * 1024 + l * 16;
  const int doffA = w * 1024 + l * 16;
  const int doffB = 8192 + w * 1024 + l * 16;
  const int roffA = wm * 4096 + l * 16;   // A frag base (granules wm*4..wm*4+3)
  const int roffB = 8192 + wn * 2048 + l * 16;

  i32x16 acc[4][2] = {};
  i32x4 a0[4], b0[2], a1[4], b1[2];  // frag double buffer (named sets)
  int4 gA0, gB0, gA1, gB1;           // staging reg pairs

  // ---- prologue: tiles 0,1 -> buf0,buf1; tile2 -> reg pair0; frags(0) ----
  {
    int4 ta0 = *(const int4*)(srcA);
    int4 tb0 = *(const int4*)(srcB);
    int4 ta1 = *(const int4*)(srcA + 8192);
    int4 tb1 = *(const int4*)(srcB + 8192);
    *(int4*)(lds + doffA) = ta0;
    *(int4*)(lds + doffB) = tb0;
    *(int4*)(lds + BUFB + doffA) = ta1;
    *(int4*)(lds + BUFB + doffB) = tb1;
    gA0 = *(const int4*)(srcA + 2 * 8192);
    gB0 = *(const int4*)(srcB + 2 * 8192);
    WAITLG0();
    SFENCE(); BAR(); SFENCE();
#pragma unroll
    for (int i = 0; i < 4; ++i)
      a0[i] = *(const i32x4*)(lds + roffA + i * 1024);
#pragma unroll
    for (int j = 0; j < 2; ++j)
      b0[j] = *(const i32x4*)(lds + roffB + j * 1024);
  }

#define STEP(KT, CA, CB, NA, NB, WA, WB, LA, LB)                               \
  do {                                                                         \
    const char* rb = lds + (((KT) + 1) & 3) * BUFB;                            \
    NA[0] = *(const i32x4*)(rb + roffA);                                       \
    NA[1] = *(const i32x4*)(rb + roffA + 1024);                                \
    NA[2] = *(const i32x4*)(rb + roffA + 2048);                                \
    NA[3] = *(const i32x4*)(rb + roffA + 3072);                                \
    NB[0] = *(const i32x4*)(rb + roffB);                                       \
    NB[1] = *(const i32x4*)(rb + roffB + 1024);                                \
    {                                                                          \
      const int ql = ((KT) + 3 > KSTEPS - 1) ? (KSTEPS - 1) : ((KT) + 3);      \
      LA = *(const int4*)(srcA + (size_t)ql * 8192);                           \
      LB = *(const int4*)(srcB + (size_t)ql * 8192);                           \
    }                                                                          \
    SFENCE();                                                                  \
    __builtin_amdgcn_s_setprio(1);                                             \
    acc[0][0] = __builtin_amdgcn_mfma_i32_32x32x32_i8(CA[0], CB[0], acc[0][0], 0, 0, 0); \
    acc[0][1] = __builtin_amdgcn_mfma_i32_32x32x32_i8(CA[0], CB[1], acc[0][1], 0, 0, 0); \
    acc[1][0] = __builtin_amdgcn_mfma_i32_32x32x32_i8(CA[1], CB[0], acc[1][0], 0, 0, 0); \
    acc[1][1] = __builtin_amdgcn_mfma_i32_32x32x32_i8(CA[1], CB[1], acc[1][1], 0, 0, 0); \
    acc[2][0] = __builtin_amdgcn_mfma_i32_32x32x32_i8(CA[2], CB[0], acc[2][0], 0, 0, 0); \
    acc[2][1] = __builtin_amdgcn_mfma_i32_32x32x32_i8(CA[2], CB[1], acc[2][1], 0, 0, 0); \
    acc[3][0] = __builtin_amdgcn_mfma_i32_32x32x32_i8(CA[3], CB[0], acc[3][0], 0, 0, 0); \
    acc[3][1] = __builtin_amdgcn_mfma_i32_32x32x32_i8(CA[3], CB[1], acc[3][1], 0, 0, 0); \
    __builtin_amdgcn_s_setprio(0);                                             \
    SFENCE();                                                                  \
    WAITVM(2);                                                                 \
    {                                                                          \
      char* wb = lds + (((KT) + 2) & 3) * BUFB;                                \
      *(int4*)(wb + doffA) = WA;                                               \
      *(int4*)(wb + doffB) = WB;                                               \
    }                                                                          \
    SFENCE();                                                                  \
    WAITLG0();                                                                 \
    SFENCE(); BAR(); SFENCE();                                                 \
  } while (0)

  for (int kt = 0; kt < KSTEPS; kt += 2) {
    STEP(kt, a0, b0, a1, b1, gA0, gB0, gA1, gB1);
    STEP(kt + 1, a1, b1, a0, b0, gA1, gB1, gA0, gB0);
  }
#undef STEP

  // epilogue: 32x32 C/D layout col = lane&31, row = (reg&3)+8*(reg>>2)+4*(lane>>5)
#pragma unroll
  for (int i = 0; i < 4; ++i) {
    const int rb = brow + wm * 128 + i * 32 + 4 * (l >> 5);
#pragma unroll
    for (int j = 0; j < 2; ++j) {
      const int col = bcol + wn * 64 + j * 32 + (l & 31);
      const float Sw = swc[col];
      const float bv = bias[col];
#pragma unroll
      for (int r = 0; r < 16; ++r) {
        const int row = rb + (r & 3) + 8 * (r >> 2);
        C[(size_t)row * N_DIM + col] = (float)acc[i][j][r] * (sxr[row] * Sw) + bv;
      }
    }
  }
}

// ---- fallback (ws too small): exact fp32, slow but correct ----
__global__ void naive_gemm(const float* __restrict__ x, const int* __restrict__ qs,
                           const float* __restrict__ scales, const float* __restrict__ bias,
                           float* __restrict__ y) {
  size_t idx = (size_t)blockIdx.x * 256 + threadIdx.x;
  if (idx >= (size_t)M_DIM * N_DIM) return;
  int o = (int)(idx % N_DIM);
  size_t m = idx / N_DIM;
  const float* xr = x + m * K_DIM;
  const int* q = qs + (size_t)o * K_DIM;
  const float* sc = scales + (size_t)o * NBLK_Q;
  float sum = 0.f;
  for (int nb = 0; nb < NBLK_Q; ++nb) {
    float s = sc[nb];
    float bs = 0.f;
#pragma unroll 8
    for (int b = 0; b < 32; ++b) bs += xr[nb * 32 + b] * (float)q[nb * 32 + b];
    sum += s * bs;
  }
  y[idx] = sum + bias[o];
}

extern "C" void kernel_launch(void* const* d_in, const int* in_sizes, int n_in,
                              void* d_out, int out_size, void* d_ws, size_t ws_size,
                              hipStream_t stream) {
  const float* x = (const float*)d_in[0];
  const int* qs = (const int*)d_in[1];
  const float* scales = (const float*)d_in[2];
  const float* bias = (const float*)d_in[3];
  float* y = (float*)d_out;

  const size_t A8_bytes = (size_t)M_DIM * K_DIM;   // 16 MB
  const size_t B8_bytes = (size_t)N_DIM * K_DIM;   // 64 MB
  const size_t SX_bytes = (size_t)M_DIM * 4;
  const size_t SW_bytes = (size_t)N_DIM * 4;

  if (ws_size < A8_bytes + B8_bytes + SX_bytes + SW_bytes) {
    size_t total = (size_t)M_DIM * N_DIM;
    naive_gemm<<<(unsigned)((total + 255) / 256), 256, 0, stream>>>(x, qs, scales, bias, y);
    return;
  }

  char* A8S = (char*)d_ws;
  char* B8S = A8S + A8_bytes;
  float* sxr = (float*)(B8S + B8_bytes);
  float* swc = (float*)((char*)sxr + SX_bytes);

  quant_x<<<M_DIM, 256, 0, stream>>>(x, A8S, sxr);
  pack_w8<<<N_DIM / 4, 256, 0, stream>>>(qs, scales, B8S, swc);
  gemm_i8<<<(M_DIM / BM) * (N_DIM / BN), 512, 0, stream>>>(A8S, B8S, sxr, swc, bias, y);
}